// Round 7
// baseline (563.006 us; speedup 1.0000x reference)
//
#include <hip/hip_runtime.h>
#include <hip/hip_bf16.h>

#define N_NODES 8192
#define NF      256
#define L2E     1.44269504088896341f

typedef __attribute__((ext_vector_type(8))) short short8;
typedef __attribute__((ext_vector_type(4))) short short4v;
typedef __attribute__((ext_vector_type(4))) float floatx4;
typedef __attribute__((ext_vector_type(16))) float floatx16;

static __device__ __forceinline__ float bf2f(short s) {
    return __uint_as_float(((unsigned)(unsigned short)s) << 16);
}
static __device__ __forceinline__ short f2bf_rn(float f) {
    unsigned u = __float_as_uint(f) + 0x8000u;
    return (short)(u >> 16);
}
struct bfpair { short hi, lo; };
static __device__ __forceinline__ bfpair split_bf(float x) {
    bfpair p;
    p.hi = f2bf_rn(x);
    p.lo = f2bf_rn(x - bf2f(p.hi));
    return p;
}
// async global->LDS, 16B/lane, LDS dest = uniform base + lane*16
static __device__ __forceinline__ void async16(const void* g, void* l) {
    __builtin_amdgcn_global_load_lds(
        (const __attribute__((address_space(1))) unsigned*)g,
        (__attribute__((address_space(3))) unsigned*)l, 16, 0, 0);
}

// ---------------------------------------------------------------------------
// KX: split W (256x256 fp32) into bf16 hi/lo arrays, once.
// ---------------------------------------------------------------------------
__global__ __launch_bounds__(256) void kx_split(const float* __restrict__ W,
                                                short* __restrict__ Whi,
                                                short* __restrict__ Wlo) {
    #pragma unroll
    for (int e = 0; e < 4; ++e) {
        const int i = blockIdx.x * 1024 + e * 256 + threadIdx.x;
        bfpair p = split_bf(W[i]);
        Whi[i] = p.hi;
        Wlo[i] = p.lo;
    }
}

// ---------------------------------------------------------------------------
// K1: WhT[n][i] = sum_k X[i][k]*W[n][k] via hi/lo bf16 MFMA (fp32-accurate).
// + per-cq partials of s_src/s_dst. (unchanged from R5)
// ---------------------------------------------------------------------------
__global__ __launch_bounds__(512) void k1_gemm(const float* __restrict__ X,
                                               const short* __restrict__ Whi,
                                               const short* __restrict__ Wlo,
                                               const float* __restrict__ r,
                                               short* __restrict__ WhT,
                                               float* __restrict__ sp_src,
                                               float* __restrict__ sp_dst) {
    __shared__ float Xs[32 * 256];

    const int tid = threadIdx.x;
    const int w = tid >> 6, lane = tid & 63;
    const int q = lane >> 4, m = lane & 15;
    const int rh = w >> 2, cq = w & 3;
    const int i_base = blockIdx.x * 32;

    #pragma unroll
    for (int v = 0; v < 4; ++v) {
        const int rowv = w * 4 + v;
        const int c = lane ^ (rowv & 7);
        async16(X + (size_t)(i_base + rowv) * NF + c * 4, &Xs[rowv * 256]);
    }
    __syncthreads();

    floatx4 acc[4] = {};
    const int xrow = rh * 16 + m;
    const int r7 = xrow & 7;
    #pragma unroll
    for (int ks = 0; ks < 8; ++ks) {
        const int c0 = ks * 8 + q * 2;
        float4 f0 = *(const float4*)(&Xs[xrow * 256 + ((c0 ^ r7) * 4)]);
        float4 f1 = *(const float4*)(&Xs[xrow * 256 + (((c0 + 1) ^ r7) * 4)]);
        const float xsv[8] = {f0.x, f0.y, f0.z, f0.w, f1.x, f1.y, f1.z, f1.w};
        short8 xh, xl;
        #pragma unroll
        for (int c = 0; c < 8; ++c) {
            bfpair p = split_bf(xsv[c]);
            xh[c] = p.hi; xl[c] = p.lo;
        }
        #pragma unroll
        for (int nt = 0; nt < 4; ++nt) {
            const int n = cq * 64 + nt * 16 + m;
            short8 wh = *(const short8*)(Whi + n * NF + ks * 32 + q * 8);
            short8 wl = *(const short8*)(Wlo + n * NF + ks * 32 + q * 8);
            acc[nt] = __builtin_amdgcn_mfma_f32_16x16x32_bf16(xh, wh, acc[nt], 0, 0, 0);
            acc[nt] = __builtin_amdgcn_mfma_f32_16x16x32_bf16(xl, wh, acc[nt], 0, 0, 0);
            acc[nt] = __builtin_amdgcn_mfma_f32_16x16x32_bf16(xh, wl, acc[nt], 0, 0, 0);
        }
    }

    const int i0 = i_base + rh * 16 + q * 4;
    float vs[4] = {0.f, 0.f, 0.f, 0.f}, vd[4] = {0.f, 0.f, 0.f, 0.f};
    #pragma unroll
    for (int nt = 0; nt < 4; ++nt) {
        const int n = cq * 64 + nt * 16 + m;
        short4v v;
        #pragma unroll
        for (int r2 = 0; r2 < 4; ++r2) v[r2] = f2bf_rn(acc[nt][r2]);
        *(short4v*)(WhT + (size_t)n * N_NODES + i0) = v;
        const float rs = r[n], rd = r[NF + n];
        #pragma unroll
        for (int r2 = 0; r2 < 4; ++r2) {
            vs[r2] = fmaf(acc[nt][r2], rs, vs[r2]);
            vd[r2] = fmaf(acc[nt][r2], rd, vd[r2]);
        }
    }
    #pragma unroll
    for (int mask = 1; mask <= 8; mask <<= 1) {
        #pragma unroll
        for (int r2 = 0; r2 < 4; ++r2) {
            vs[r2] += __shfl_xor(vs[r2], mask);
            vd[r2] += __shfl_xor(vd[r2], mask);
        }
    }
    if (m == 0) {
        #pragma unroll
        for (int r2 = 0; r2 < 4; ++r2) {
            sp_src[cq * N_NODES + i0 + r2] = vs[r2];
            sp_dst[cq * N_NODES + i0 + r2] = vd[r2];
        }
    }
}

// ---------------------------------------------------------------------------
// K2: sum 4 partials -> s_src/s_dst; per-block max(s_dst) -> pmax[32]
// ---------------------------------------------------------------------------
__global__ __launch_bounds__(256) void k2_sv(const float* __restrict__ sp_src,
                                             const float* __restrict__ sp_dst,
                                             float* __restrict__ s_src,
                                             float* __restrict__ s_dst,
                                             float* __restrict__ pmax) {
    __shared__ float red[256];
    const int tid = threadIdx.x;
    const int i = blockIdx.x * 256 + tid;
    float ss = 0.f, sd = 0.f;
    #pragma unroll
    for (int nb = 0; nb < 4; ++nb) {
        ss += sp_src[nb * N_NODES + i];
        sd += sp_dst[nb * N_NODES + i];
    }
    s_src[i] = ss;
    s_dst[i] = sd;
    red[tid] = sd;
    __syncthreads();
    for (int off = 128; off > 0; off >>= 1) {
        if (tid < off) red[tid] = fmaxf(red[tid], red[tid + off]);
        __syncthreads();
    }
    if (tid == 0) pmax[blockIdx.x] = red[0];
}

// ---------------------------------------------------------------------------
// K4: fused masked-softmax attention + PV (32x32x16 MFMA) + exact GELU.
// grid 256 x 1024 (16 waves = 4 nq x 4 jg). Block owns 32 rows.
// Macro = 128 j. B double-buffered in LDS (2x64KB), async16 staged,
// ONE barrier per macro. A register-prefetched one macro ahead.
// 32x32 A-frag: row=lane&31, k=(lane>>5)*8+idx.
// 32x32 C/D:    col=lane&31, row=(reg&3)+8*(reg>>2)+4*(lane>>5).
// NOTE: P (and den) depend only on jg — den must be reduced over the 4 jg
// waves at nq==0 ONLY (R6 bug: summing all 16 waves counted each j 4x).
// ---------------------------------------------------------------------------
static __device__ __forceinline__ void pgroup(const int4 a, const floatx4 t,
                                              const float s_i, const float d_i,
                                              float* p) {
    const int av[4] = {a.x, a.y, a.z, a.w};
    #pragma unroll
    for (int c = 0; c < 4; ++c) {
        float sum = s_i + t[c];
        float lr  = fmaxf(sum, 0.2f * sum);
        float pp  = __builtin_amdgcn_exp2f(fmaf(lr, L2E, d_i));
        p[c] = (av[c] != 0) ? pp : 0.0f;
    }
}

__global__ __launch_bounds__(1024) void k4_attn(const int* __restrict__ Adj,
                                                const short* __restrict__ WhT,
                                                const float* __restrict__ s_dst,
                                                const float* __restrict__ s_src,
                                                const float* __restrict__ pmax,
                                                float* __restrict__ out) {
    __shared__ union {
        short B[2][256 * 128];   // [buf][n][16 slots of 8 j-shorts], slot=c^(n&15)
        float red[32768];        // epilogue: [w][nt][rq][lane][4]
    } sm;
    __shared__ float denred[16 * 32];
    __shared__ float invden[32];

    const int tid = threadIdx.x;
    const int w = tid >> 6, lane = tid & 63;
    const int nq = w & 3, jg = w >> 2;
    const int l31 = lane & 31, lh = lane >> 5, l15 = lane & 15;
    const int i0 = blockIdx.x * 32;
    const int row = i0 + l31;

    float M = pmax[0];
    #pragma unroll
    for (int b = 1; b < 32; ++b) M = fmaxf(M, pmax[b]);
    const float s_i = s_src[row];
    const float e0 = s_i + M;
    const float d_i = -fmaxf(e0, 0.2f * e0) * L2E;   // c_i >= row max (leaky monotone)

    // staging source pointers (wave w stages rows w*16..w*16+16)
    const short* gB[4];
    #pragma unroll
    for (int v = 0; v < 4; ++v) {
        const int nlo = v * 4 + (lane >> 4);             // n & 15
        const int c = l15 ^ nlo;                         // global 16B chunk
        gB[v] = WhT + (size_t)(w * 16 + nlo) * N_NODES + c * 8;
    }

    // frag read offsets (shorts), invariant: slot = jc ^ (n&15), n&15 == l15
    const int jcA = jg * 4 + lh;
    int boff0[2], boff1[2];
    #pragma unroll
    for (int nt = 0; nt < 2; ++nt) {
        const int n = nq * 64 + nt * 32 + l31;
        boff0[nt] = n * 128 + ((jcA ^ l15) * 8);
        boff1[nt] = n * 128 + (((jcA + 2) ^ l15) * 8);
    }

    const int* aB = Adj + (size_t)row * N_NODES + jg * 32 + lh * 8;
    const float* tB = s_dst + jg * 32 + lh * 8;

    floatx16 acc0 = {}, acc1 = {};
    float den = 0.f;

    // prologue: stage macro 0 into buf 0, prefetch A(0)
    #pragma unroll
    for (int v = 0; v < 4; ++v)
        async16(gB[v], &sm.B[0][(w * 16 + v * 4) * 128]);
    int4 a0 = *(const int4*)(aB);
    int4 a1 = *(const int4*)(aB + 4);
    int4 a2 = *(const int4*)(aB + 16);
    int4 a3 = *(const int4*)(aB + 20);
    __syncthreads();

    for (int s = 0; s < 64; ++s) {
        const short* Bc = sm.B[s & 1];
        short* Bn = sm.B[(s & 1) ^ 1];

        // stage next macro's B (lands during this macro's compute)
        if (s < 63) {
            const int jn = (s + 1) * 128;
            #pragma unroll
            for (int v = 0; v < 4; ++v)
                async16(gB[v] + jn, Bn + (w * 16 + v * 4) * 128);
        }
        // prefetch next macro's A into registers
        const int an = (s < 63) ? (s + 1) * 128 : s * 128;
        int4 na0 = *(const int4*)(aB + an);
        int4 na1 = *(const int4*)(aB + an + 4);
        int4 na2 = *(const int4*)(aB + an + 16);
        int4 na3 = *(const int4*)(aB + an + 20);
        // t for this macro (L2-hot)
        const float* tp = tB + s * 128;
        floatx4 t0 = *(const floatx4*)(tp);
        floatx4 t1 = *(const floatx4*)(tp + 4);
        floatx4 t2 = *(const floatx4*)(tp + 16);
        floatx4 t3 = *(const floatx4*)(tp + 20);

        float p[16];
        pgroup(a0, t0, s_i, d_i, p);
        pgroup(a1, t1, s_i, d_i, p + 4);
        pgroup(a2, t2, s_i, d_i, p + 8);
        pgroup(a3, t3, s_i, d_i, p + 12);

        short8 af0, af1;
        #pragma unroll
        for (int c = 0; c < 8; ++c) { af0[c] = f2bf_rn(p[c]); af1[c] = f2bf_rn(p[8 + c]); }
        float ds = 0.f;
        #pragma unroll
        for (int c = 0; c < 16; ++c) ds += p[c];
        den += ds;

        {
            short8 b0 = *(const short8*)(Bc + boff0[0]);
            short8 b1 = *(const short8*)(Bc + boff1[0]);
            acc0 = __builtin_amdgcn_mfma_f32_32x32x16_bf16(af0, b0, acc0, 0, 0, 0);
            acc0 = __builtin_amdgcn_mfma_f32_32x32x16_bf16(af1, b1, acc0, 0, 0, 0);
        }
        {
            short8 b0 = *(const short8*)(Bc + boff0[1]);
            short8 b1 = *(const short8*)(Bc + boff1[1]);
            acc1 = __builtin_amdgcn_mfma_f32_32x32x16_bf16(af0, b0, acc1, 0, 0, 0);
            acc1 = __builtin_amdgcn_mfma_f32_32x32x16_bf16(af1, b1, acc1, 0, 0, 0);
        }
        a0 = na0; a1 = na1; a2 = na2; a3 = na3;

        __syncthreads();   // frag reads of Bc done; staging into Bn landed
    }

    // ---- denominator: lane partial covers row l31, its (jg, lh) j-slice
    den += __shfl_xor(den, 32);
    if (lane < 32) denred[w * 32 + lane] = den;
    __syncthreads();
    if (tid < 32) {
        float d = 0.f;
        // sum ONLY the nq==0 waves (w = jg*4): the 4 jg slices tile j-space;
        // nq duplicates must not be counted (R6 bug: 4x den).
        #pragma unroll
        for (int u = 0; u < 4; ++u) d += denred[(u * 4) * 32 + tid];
        invden[tid] = 1.0f / fmaxf(d, 1e-30f);
    }

    // ---- write acc partials: [w][nt][rq][lane][4]
    #pragma unroll
    for (int rq = 0; rq < 4; ++rq) {
        float4 v0, v1;
        v0.x = acc0[rq * 4 + 0]; v0.y = acc0[rq * 4 + 1];
        v0.z = acc0[rq * 4 + 2]; v0.w = acc0[rq * 4 + 3];
        v1.x = acc1[rq * 4 + 0]; v1.y = acc1[rq * 4 + 1];
        v1.z = acc1[rq * 4 + 2]; v1.w = acc1[rq * 4 + 3];
        *(float4*)(&sm.red[(((w * 2 + 0) * 4 + rq) * 64 + lane) * 4]) = v0;
        *(float4*)(&sm.red[(((w * 2 + 1) * 4 + rq) * 64 + lane) * 4]) = v1;
    }
    __syncthreads();

    // ---- sum 4 jg-partials, GELU, store. wave (nq,jg): nt=jg&1, rq={jg>>1, 2+(jg>>1)}
    const int ntw = jg & 1;
    #pragma unroll
    for (int h = 0; h < 2; ++h) {
        const int rq = (jg >> 1) + h * 2;
        float4 v = {0.f, 0.f, 0.f, 0.f};
        #pragma unroll
        for (int jg2 = 0; jg2 < 4; ++jg2) {
            const int wp = jg2 * 4 + nq;
            float4 u = *(const float4*)(&sm.red[(((wp * 2 + ntw) * 4 + rq) * 64 + lane) * 4]);
            v.x += u.x; v.y += u.y; v.z += u.z; v.w += u.w;
        }
        const int n = nq * 64 + ntw * 32 + l31;
        const float vv[4] = {v.x, v.y, v.z, v.w};
        #pragma unroll
        for (int t = 0; t < 4; ++t) {
            const int rrow = t + 8 * rq + 4 * lh;
            float x = vv[t] * invden[rrow];
            float g = 0.5f * x * (1.0f + erff(x * 0.70710678118f)); // exact GELU
            out[(size_t)(i0 + rrow) * NF + n] = g;
        }
    }
}

// ---------------------------------------------------------------------------
extern "C" void kernel_launch(void* const* d_in, const int* in_sizes, int n_in,
                              void* d_out, int out_size, void* d_ws, size_t ws_size,
                              hipStream_t stream) {
    const float* X = (const float*)d_in[0];   // fp32 8192x256
    const int*   A = (const int*)d_in[1];     // int32 8192x8192
    const float* W = (const float*)d_in[2];   // fp32 256x256
    const float* r = (const float*)d_in[3];   // fp32 512
    float* out = (float*)d_out;

    char* wsp = (char*)d_ws;
    short* WhT    = (short*)wsp;                    wsp += (size_t)NF * N_NODES * 2;
    short* Whi    = (short*)wsp;                    wsp += NF * NF * 2;
    short* Wlo    = (short*)wsp;                    wsp += NF * NF * 2;
    float* sp_src = (float*)wsp;                    wsp += 4 * N_NODES * 4;
    float* sp_dst = (float*)wsp;                    wsp += 4 * N_NODES * 4;
    float* s_src  = (float*)wsp;                    wsp += N_NODES * 4;
    float* s_dst  = (float*)wsp;                    wsp += N_NODES * 4;
    float* pmax   = (float*)wsp;

    kx_split<<<64, 256, 0, stream>>>(W, Whi, Wlo);
    k1_gemm<<<256, 512, 0, stream>>>(X, Whi, Wlo, r, WhT, sp_src, sp_dst);
    k2_sv<<<32, 256, 0, stream>>>(sp_src, sp_dst, s_src, s_dst, pmax);
    k4_attn<<<256, 1024, 0, stream>>>(A, WhT, s_dst, s_src, pmax, out);
}

// Round 8
// 495.479 us; speedup vs baseline: 1.1363x; 1.1363x over previous
//
#include <hip/hip_runtime.h>
#include <hip/hip_bf16.h>

#define N_NODES 8192
#define NF      256
#define L2E     1.44269504088896341f

typedef __attribute__((ext_vector_type(8))) short short8;
typedef __attribute__((ext_vector_type(4))) short short4v;
typedef __attribute__((ext_vector_type(4))) float floatx4;
typedef __attribute__((ext_vector_type(16))) float floatx16;

static __device__ __forceinline__ float bf2f(short s) {
    return __uint_as_float(((unsigned)(unsigned short)s) << 16);
}
static __device__ __forceinline__ short f2bf_rn(float f) {
    unsigned u = __float_as_uint(f) + 0x8000u;
    return (short)(u >> 16);
}
struct bfpair { short hi, lo; };
static __device__ __forceinline__ bfpair split_bf(float x) {
    bfpair p;
    p.hi = f2bf_rn(x);
    p.lo = f2bf_rn(x - bf2f(p.hi));
    return p;
}
// async global->LDS, 16B/lane, LDS dest = uniform base + lane*16
static __device__ __forceinline__ void async16(const void* g, void* l) {
    __builtin_amdgcn_global_load_lds(
        (const __attribute__((address_space(1))) unsigned*)g,
        (__attribute__((address_space(3))) unsigned*)l, 16, 0, 0);
}

// ---------------------------------------------------------------------------
// KX: split W into bf16 hi/lo, once.
// ---------------------------------------------------------------------------
__global__ __launch_bounds__(256) void kx_split(const float* __restrict__ W,
                                                short* __restrict__ Whi,
                                                short* __restrict__ Wlo) {
    #pragma unroll
    for (int e = 0; e < 4; ++e) {
        const int i = blockIdx.x * 1024 + e * 256 + threadIdx.x;
        bfpair p = split_bf(W[i]);
        Whi[i] = p.hi;
        Wlo[i] = p.lo;
    }
}

// ---------------------------------------------------------------------------
// K1: WhT[n][i] = X@W^T via hi/lo bf16 MFMA + s partials. (unchanged)
// ---------------------------------------------------------------------------
__global__ __launch_bounds__(512) void k1_gemm(const float* __restrict__ X,
                                               const short* __restrict__ Whi,
                                               const short* __restrict__ Wlo,
                                               const float* __restrict__ r,
                                               short* __restrict__ WhT,
                                               float* __restrict__ sp_src,
                                               float* __restrict__ sp_dst) {
    __shared__ float Xs[32 * 256];

    const int tid = threadIdx.x;
    const int w = tid >> 6, lane = tid & 63;
    const int q = lane >> 4, m = lane & 15;
    const int rh = w >> 2, cq = w & 3;
    const int i_base = blockIdx.x * 32;

    #pragma unroll
    for (int v = 0; v < 4; ++v) {
        const int rowv = w * 4 + v;
        const int c = lane ^ (rowv & 7);
        async16(X + (size_t)(i_base + rowv) * NF + c * 4, &Xs[rowv * 256]);
    }
    __syncthreads();

    floatx4 acc[4] = {};
    const int xrow = rh * 16 + m;
    const int r7 = xrow & 7;
    #pragma unroll
    for (int ks = 0; ks < 8; ++ks) {
        const int c0 = ks * 8 + q * 2;
        float4 f0 = *(const float4*)(&Xs[xrow * 256 + ((c0 ^ r7) * 4)]);
        float4 f1 = *(const float4*)(&Xs[xrow * 256 + (((c0 + 1) ^ r7) * 4)]);
        const float xsv[8] = {f0.x, f0.y, f0.z, f0.w, f1.x, f1.y, f1.z, f1.w};
        short8 xh, xl;
        #pragma unroll
        for (int c = 0; c < 8; ++c) {
            bfpair p = split_bf(xsv[c]);
            xh[c] = p.hi; xl[c] = p.lo;
        }
        #pragma unroll
        for (int nt = 0; nt < 4; ++nt) {
            const int n = cq * 64 + nt * 16 + m;
            short8 wh = *(const short8*)(Whi + n * NF + ks * 32 + q * 8);
            short8 wl = *(const short8*)(Wlo + n * NF + ks * 32 + q * 8);
            acc[nt] = __builtin_amdgcn_mfma_f32_16x16x32_bf16(xh, wh, acc[nt], 0, 0, 0);
            acc[nt] = __builtin_amdgcn_mfma_f32_16x16x32_bf16(xl, wh, acc[nt], 0, 0, 0);
            acc[nt] = __builtin_amdgcn_mfma_f32_16x16x32_bf16(xh, wl, acc[nt], 0, 0, 0);
        }
    }

    const int i0 = i_base + rh * 16 + q * 4;
    float vs[4] = {0.f, 0.f, 0.f, 0.f}, vd[4] = {0.f, 0.f, 0.f, 0.f};
    #pragma unroll
    for (int nt = 0; nt < 4; ++nt) {
        const int n = cq * 64 + nt * 16 + m;
        short4v v;
        #pragma unroll
        for (int r2 = 0; r2 < 4; ++r2) v[r2] = f2bf_rn(acc[nt][r2]);
        *(short4v*)(WhT + (size_t)n * N_NODES + i0) = v;
        const float rs = r[n], rd = r[NF + n];
        #pragma unroll
        for (int r2 = 0; r2 < 4; ++r2) {
            vs[r2] = fmaf(acc[nt][r2], rs, vs[r2]);
            vd[r2] = fmaf(acc[nt][r2], rd, vd[r2]);
        }
    }
    #pragma unroll
    for (int mask = 1; mask <= 8; mask <<= 1) {
        #pragma unroll
        for (int r2 = 0; r2 < 4; ++r2) {
            vs[r2] += __shfl_xor(vs[r2], mask);
            vd[r2] += __shfl_xor(vd[r2], mask);
        }
    }
    if (m == 0) {
        #pragma unroll
        for (int r2 = 0; r2 < 4; ++r2) {
            sp_src[cq * N_NODES + i0 + r2] = vs[r2];
            sp_dst[cq * N_NODES + i0 + r2] = vd[r2];
        }
    }
}

// ---------------------------------------------------------------------------
// K2: sum partials -> s_src/s_dst; per-block max(s_dst) -> pmax[32]
// ---------------------------------------------------------------------------
__global__ __launch_bounds__(256) void k2_sv(const float* __restrict__ sp_src,
                                             const float* __restrict__ sp_dst,
                                             float* __restrict__ s_src,
                                             float* __restrict__ s_dst,
                                             float* __restrict__ pmax) {
    __shared__ float red[256];
    const int tid = threadIdx.x;
    const int i = blockIdx.x * 256 + tid;
    float ss = 0.f, sd = 0.f;
    #pragma unroll
    for (int nb = 0; nb < 4; ++nb) {
        ss += sp_src[nb * N_NODES + i];
        sd += sp_dst[nb * N_NODES + i];
    }
    s_src[i] = ss;
    s_dst[i] = sd;
    red[tid] = sd;
    __syncthreads();
    for (int off = 128; off > 0; off >>= 1) {
        if (tid < off) red[tid] = fmaxf(red[tid], red[tid + off]);
        __syncthreads();
    }
    if (tid == 0) pmax[blockIdx.x] = red[0];
}

// ---------------------------------------------------------------------------
// K4: fused masked-softmax numerator/denominator partials (32x32x16 MFMA).
// grid 512 = 256 i-tiles x 2 j-halves; 512 thr (8 waves = 4 jq x 2 nh).
// Block: 32 rows x 4096 j. Macro = 128 j; B-tile 256n x 128j = 64 KB LDS,
// single-buffered, async16-staged, 2 barriers/macro; 2 blocks/CU overlap.
// P dup 2x (nh), A dup 2x, B LDS-read : staged = 1:1.
// A-frag(32x32): row=lane&31, k=(lane>>5)*8+idx. C/D: col=lane&31,
// row=(reg&3)+8*(reg>>2)+4*(lane>>5).
// ---------------------------------------------------------------------------
static __device__ __forceinline__ void pgroup(const int4 a, const floatx4 t,
                                              const float s_i, const float d_i,
                                              float* p) {
    const int av[4] = {a.x, a.y, a.z, a.w};
    #pragma unroll
    for (int c = 0; c < 4; ++c) {
        float sum = s_i + t[c];
        float lr  = fmaxf(sum, 0.2f * sum);
        float pp  = __builtin_amdgcn_exp2f(fmaf(lr, L2E, d_i));
        p[c] = (av[c] != 0) ? pp : 0.0f;
    }
}

__global__ __launch_bounds__(512, 4) void k4_attn(const int* __restrict__ Adj,
                                                  const short* __restrict__ WhT,
                                                  const float* __restrict__ s_dst,
                                                  const float* __restrict__ s_src,
                                                  const float* __restrict__ pmax,
                                                  float* __restrict__ nump,
                                                  float* __restrict__ denp) {
    __shared__ union {
        short B[256 * 128];   // [n][16 slots x 8 j-shorts], slot = c ^ (n&15); 64 KB
        float red[8 * 16 * 64]; // epilogue pass: [w][reg][lane]; 32 KB
    } sm;
    __shared__ float denred[4 * 32];

    const int tid = threadIdx.x;
    const int w = tid >> 6, lane = tid & 63;
    const int jq = w & 3, nh = w >> 2;
    const int l31 = lane & 31, lh = lane >> 5, l15 = lane & 15;
    const int ib = (int)blockIdx.x >> 1, jh = (int)blockIdx.x & 1;
    const int i0 = ib * 32;
    const int row = i0 + l31;
    const int jbase = jh * 4096;

    float M = pmax[0];
    #pragma unroll
    for (int b = 1; b < 32; ++b) M = fmaxf(M, pmax[b]);
    const float s_i = s_src[row];
    const float e0 = s_i + M;
    const float d_i = -fmaxf(e0, 0.2f * e0) * L2E;   // c_i >= row max (leaky monotone)

    // staging: wave stages n-rows w*32..w*32+31, 8 async16
    int voff[8];
    #pragma unroll
    for (int v = 0; v < 8; ++v) {
        const int n = w * 32 + v * 4 + (lane >> 4);
        const int c = l15 ^ (n & 15);
        voff[v] = n * N_NODES + c * 8;               // short offset
    }
    const short* gBbase = WhT + jbase;

    // frag-read LDS offsets (shorts); n&15 == l15 for all nt/nh
    const int slot0 = (jq * 4 + lh) ^ l15;
    const int slot1 = (jq * 4 + 2 + lh) ^ l15;
    const int nrow = nh * 128 + l31;
    const int boffA = nrow * 128 + slot0 * 8;
    const int boffB = nrow * 128 + slot1 * 8;

    const int* aPtr = Adj + (size_t)row * N_NODES + jbase + jq * 32 + lh * 8;
    const float* tPtr = s_dst + jbase + jq * 32 + lh * 8;

    floatx16 acc[4] = {};
    float den = 0.f;

    for (int s = 0; s < 32; ++s) {
        const int jo = s * 128;
        // stage macro s into LDS
        #pragma unroll
        for (int v = 0; v < 8; ++v)
            async16(gBbase + jo + voff[v], sm.B + (w * 32 + v * 4) * 128);
        __syncthreads();   // staging drained (other co-resident block computes)

        // A (HBM stream) + t (L2-hot) for this macro
        int4 a0 = *(const int4*)(aPtr + jo);
        int4 a1 = *(const int4*)(aPtr + jo + 4);
        int4 a2 = *(const int4*)(aPtr + jo + 16);
        int4 a3 = *(const int4*)(aPtr + jo + 20);
        floatx4 t0 = *(const floatx4*)(tPtr + jo);
        floatx4 t1 = *(const floatx4*)(tPtr + jo + 4);
        floatx4 t2 = *(const floatx4*)(tPtr + jo + 16);
        floatx4 t3 = *(const floatx4*)(tPtr + jo + 20);

        float p[16];
        pgroup(a0, t0, s_i, d_i, p);
        pgroup(a1, t1, s_i, d_i, p + 4);
        pgroup(a2, t2, s_i, d_i, p + 8);
        pgroup(a3, t3, s_i, d_i, p + 12);

        short8 af0, af1;
        #pragma unroll
        for (int c = 0; c < 8; ++c) { af0[c] = f2bf_rn(p[c]); af1[c] = f2bf_rn(p[8 + c]); }
        float ds = 0.f;
        #pragma unroll
        for (int c = 0; c < 16; ++c) ds += p[c];
        den += ds;

        #pragma unroll
        for (int nt = 0; nt < 4; ++nt) {
            short8 b0 = *(const short8*)(sm.B + boffA + nt * 4096);
            short8 b1 = *(const short8*)(sm.B + boffB + nt * 4096);
            acc[nt] = __builtin_amdgcn_mfma_f32_32x32x16_bf16(af0, b0, acc[nt], 0, 0, 0);
            acc[nt] = __builtin_amdgcn_mfma_f32_32x32x16_bf16(af1, b1, acc[nt], 0, 0, 0);
        }
        __syncthreads();   // all B reads done before next stage overwrites
    }

    // ---- denominator partial (nh==0 waves only; jq slices tile j) ----
    den += __shfl_xor(den, 32);
    if (w < 4 && lane < 32) denred[w * 32 + lane] = den;

    // ---- numerator: reduce 4 jq partials per nt via LDS, store to nump[jh]
    float* numq = nump + (size_t)jh * N_NODES * NF;
    #pragma unroll
    for (int nt = 0; nt < 4; ++nt) {
        #pragma unroll
        for (int rg = 0; rg < 16; ++rg)
            sm.red[(w * 16 + rg) * 64 + lane] = acc[nt][rg];
        __syncthreads();
        if (nt == 0 && tid < 32) {
            float d = denred[tid] + denred[32 + tid] + denred[64 + tid] + denred[96 + tid];
            denp[jh * N_NODES + i0 + tid] = d;
        }
        // wave w reduces: nh2 = w&1, regs (w>>1)*4..+3
        const int nh2 = w & 1;
        const int rb = (w >> 1) * 4;
        #pragma unroll
        for (int k = 0; k < 4; ++k) {
            const int rg = rb + k;
            float v = sm.red[((nh2 * 4 + 0) * 16 + rg) * 64 + lane]
                    + sm.red[((nh2 * 4 + 1) * 16 + rg) * 64 + lane]
                    + sm.red[((nh2 * 4 + 2) * 16 + rg) * 64 + lane]
                    + sm.red[((nh2 * 4 + 3) * 16 + rg) * 64 + lane];
            const int rrow = (rg & 3) + 8 * (rg >> 2) + 4 * lh;
            const int nn = nh2 * 128 + nt * 32 + l31;
            numq[(size_t)(i0 + rrow) * NF + nn] = v;
        }
        __syncthreads();
    }
}

// ---------------------------------------------------------------------------
// K5: out = GELU( (num0+num1) / (den0+den1) )
// ---------------------------------------------------------------------------
__global__ __launch_bounds__(256) void k5_out(const float* __restrict__ nump,
                                              const float* __restrict__ denp,
                                              float* __restrict__ out) {
    const int idx = blockIdx.x * 256 + threadIdx.x;
    const int i = idx >> 8;
    float num = nump[idx] + nump[N_NODES * NF + idx];
    float den = denp[i] + denp[N_NODES + i];
    float x = num / fmaxf(den, 1e-30f);
    out[idx] = 0.5f * x * (1.0f + erff(x * 0.70710678118f));
}

// ---------------------------------------------------------------------------
extern "C" void kernel_launch(void* const* d_in, const int* in_sizes, int n_in,
                              void* d_out, int out_size, void* d_ws, size_t ws_size,
                              hipStream_t stream) {
    const float* X = (const float*)d_in[0];   // fp32 8192x256
    const int*   A = (const int*)d_in[1];     // int32 8192x8192
    const float* W = (const float*)d_in[2];   // fp32 256x256
    const float* r = (const float*)d_in[3];   // fp32 512
    float* out = (float*)d_out;

    char* wsp = (char*)d_ws;
    short* WhT    = (short*)wsp;                    wsp += (size_t)NF * N_NODES * 2;
    short* Whi    = (short*)wsp;                    wsp += NF * NF * 2;
    short* Wlo    = (short*)wsp;                    wsp += NF * NF * 2;
    float* sp_src = (float*)wsp;                    wsp += 4 * N_NODES * 4;
    float* sp_dst = (float*)wsp;                    wsp += 4 * N_NODES * 4;
    float* s_src  = (float*)wsp;                    wsp += N_NODES * 4;
    float* s_dst  = (float*)wsp;                    wsp += N_NODES * 4;
    float* pmax   = (float*)wsp;                    wsp += 32 * 4;
    float* denp   = (float*)wsp;                    wsp += 2 * N_NODES * 4;
    float* nump   = (float*)wsp;  // 2 x 8192 x 256 fp32 = 16 MB

    kx_split<<<64, 256, 0, stream>>>(W, Whi, Wlo);
    k1_gemm<<<256, 512, 0, stream>>>(X, Whi, Wlo, r, WhT, sp_src, sp_dst);
    k2_sv<<<32, 256, 0, stream>>>(sp_src, sp_dst, s_src, s_dst, pmax);
    k4_attn<<<512, 512, 0, stream>>>(A, WhT, s_dst, s_src, pmax, nump, denp);
    k5_out<<<N_NODES * NF / 256, 256, 0, stream>>>(nump, denp, out);
}

// Round 9
// 488.196 us; speedup vs baseline: 1.1532x; 1.0149x over previous
//
#include <hip/hip_runtime.h>
#include <hip/hip_bf16.h>

#define N_NODES 8192
#define NF      256
#define L2E     1.44269504088896341f

typedef __attribute__((ext_vector_type(8))) short short8;
typedef __attribute__((ext_vector_type(4))) short short4v;
typedef __attribute__((ext_vector_type(4))) float floatx4;
typedef __attribute__((ext_vector_type(16))) float floatx16;

static __device__ __forceinline__ float bf2f(short s) {
    return __uint_as_float(((unsigned)(unsigned short)s) << 16);
}
static __device__ __forceinline__ short f2bf_rn(float f) {
    unsigned u = __float_as_uint(f) + 0x8000u;
    return (short)(u >> 16);
}
struct bfpair { short hi, lo; };
static __device__ __forceinline__ bfpair split_bf(float x) {
    bfpair p;
    p.hi = f2bf_rn(x);
    p.lo = f2bf_rn(x - bf2f(p.hi));
    return p;
}
// async global->LDS, 16B/lane, LDS dest = uniform base + lane*16
static __device__ __forceinline__ void async16(const void* g, void* l) {
    __builtin_amdgcn_global_load_lds(
        (const __attribute__((address_space(1))) unsigned*)g,
        (__attribute__((address_space(3))) unsigned*)l, 16, 0, 0);
}

// ---------------------------------------------------------------------------
// KX: split W into bf16 hi/lo, once.
// ---------------------------------------------------------------------------
__global__ __launch_bounds__(256) void kx_split(const float* __restrict__ W,
                                                short* __restrict__ Whi,
                                                short* __restrict__ Wlo) {
    #pragma unroll
    for (int e = 0; e < 4; ++e) {
        const int i = blockIdx.x * 1024 + e * 256 + threadIdx.x;
        bfpair p = split_bf(W[i]);
        Whi[i] = p.hi;
        Wlo[i] = p.lo;
    }
}

// ---------------------------------------------------------------------------
// K1: WhT[n][i] = X@W^T via hi/lo bf16 MFMA + s partials. (unchanged)
// ---------------------------------------------------------------------------
__global__ __launch_bounds__(512) void k1_gemm(const float* __restrict__ X,
                                               const short* __restrict__ Whi,
                                               const short* __restrict__ Wlo,
                                               const float* __restrict__ r,
                                               short* __restrict__ WhT,
                                               float* __restrict__ sp_src,
                                               float* __restrict__ sp_dst) {
    __shared__ float Xs[32 * 256];

    const int tid = threadIdx.x;
    const int w = tid >> 6, lane = tid & 63;
    const int q = lane >> 4, m = lane & 15;
    const int rh = w >> 2, cq = w & 3;
    const int i_base = blockIdx.x * 32;

    #pragma unroll
    for (int v = 0; v < 4; ++v) {
        const int rowv = w * 4 + v;
        const int c = lane ^ (rowv & 7);
        async16(X + (size_t)(i_base + rowv) * NF + c * 4, &Xs[rowv * 256]);
    }
    __syncthreads();

    floatx4 acc[4] = {};
    const int xrow = rh * 16 + m;
    const int r7 = xrow & 7;
    #pragma unroll
    for (int ks = 0; ks < 8; ++ks) {
        const int c0 = ks * 8 + q * 2;
        float4 f0 = *(const float4*)(&Xs[xrow * 256 + ((c0 ^ r7) * 4)]);
        float4 f1 = *(const float4*)(&Xs[xrow * 256 + (((c0 + 1) ^ r7) * 4)]);
        const float xsv[8] = {f0.x, f0.y, f0.z, f0.w, f1.x, f1.y, f1.z, f1.w};
        short8 xh, xl;
        #pragma unroll
        for (int c = 0; c < 8; ++c) {
            bfpair p = split_bf(xsv[c]);
            xh[c] = p.hi; xl[c] = p.lo;
        }
        #pragma unroll
        for (int nt = 0; nt < 4; ++nt) {
            const int n = cq * 64 + nt * 16 + m;
            short8 wh = *(const short8*)(Whi + n * NF + ks * 32 + q * 8);
            short8 wl = *(const short8*)(Wlo + n * NF + ks * 32 + q * 8);
            acc[nt] = __builtin_amdgcn_mfma_f32_16x16x32_bf16(xh, wh, acc[nt], 0, 0, 0);
            acc[nt] = __builtin_amdgcn_mfma_f32_16x16x32_bf16(xl, wh, acc[nt], 0, 0, 0);
            acc[nt] = __builtin_amdgcn_mfma_f32_16x16x32_bf16(xh, wl, acc[nt], 0, 0, 0);
        }
    }

    const int i0 = i_base + rh * 16 + q * 4;
    float vs[4] = {0.f, 0.f, 0.f, 0.f}, vd[4] = {0.f, 0.f, 0.f, 0.f};
    #pragma unroll
    for (int nt = 0; nt < 4; ++nt) {
        const int n = cq * 64 + nt * 16 + m;
        short4v v;
        #pragma unroll
        for (int r2 = 0; r2 < 4; ++r2) v[r2] = f2bf_rn(acc[nt][r2]);
        *(short4v*)(WhT + (size_t)n * N_NODES + i0) = v;
        const float rs = r[n], rd = r[NF + n];
        #pragma unroll
        for (int r2 = 0; r2 < 4; ++r2) {
            vs[r2] = fmaf(acc[nt][r2], rs, vs[r2]);
            vd[r2] = fmaf(acc[nt][r2], rd, vd[r2]);
        }
    }
    #pragma unroll
    for (int mask = 1; mask <= 8; mask <<= 1) {
        #pragma unroll
        for (int r2 = 0; r2 < 4; ++r2) {
            vs[r2] += __shfl_xor(vs[r2], mask);
            vd[r2] += __shfl_xor(vd[r2], mask);
        }
    }
    if (m == 0) {
        #pragma unroll
        for (int r2 = 0; r2 < 4; ++r2) {
            sp_src[cq * N_NODES + i0 + r2] = vs[r2];
            sp_dst[cq * N_NODES + i0 + r2] = vd[r2];
        }
    }
}

// ---------------------------------------------------------------------------
// K2: sum partials -> s_src/s_dst; per-block max(s_dst) -> pmax[32]
// ---------------------------------------------------------------------------
__global__ __launch_bounds__(256) void k2_sv(const float* __restrict__ sp_src,
                                             const float* __restrict__ sp_dst,
                                             float* __restrict__ s_src,
                                             float* __restrict__ s_dst,
                                             float* __restrict__ pmax) {
    __shared__ float red[256];
    const int tid = threadIdx.x;
    const int i = blockIdx.x * 256 + tid;
    float ss = 0.f, sd = 0.f;
    #pragma unroll
    for (int nb = 0; nb < 4; ++nb) {
        ss += sp_src[nb * N_NODES + i];
        sd += sp_dst[nb * N_NODES + i];
    }
    s_src[i] = ss;
    s_dst[i] = sd;
    red[tid] = sd;
    __syncthreads();
    for (int off = 128; off > 0; off >>= 1) {
        if (tid < off) red[tid] = fmaxf(red[tid], red[tid + off]);
        __syncthreads();
    }
    if (tid == 0) pmax[blockIdx.x] = red[0];
}

// ---------------------------------------------------------------------------
// K4: fused masked-softmax num/den partials (32x32x16 MFMA).
// grid 512 = 256 i-tiles x 2 j-halves; 512 thr (8 waves = 4 jq x 2 nh).
// Block: 32 rows x 4096 j. Macro = 64 j. B double-buffered 2x32KB (66KB LDS
// -> 2 blocks/CU), async16-staged one macro AHEAD, ONE barrier per macro.
// A register-prefetched one macro ahead (hides ~900cyc HBM latency).
// A-frag(32x32): row=lane&31, k=(lane>>5)*8+idx. C/D: col=lane&31,
// row=(reg&3)+8*(reg>>2)+4*(lane>>5).
// ---------------------------------------------------------------------------
static __device__ __forceinline__ void pgroup(const int4 a, const floatx4 t,
                                              const float s_i, const float d_i,
                                              float* p) {
    const int av[4] = {a.x, a.y, a.z, a.w};
    #pragma unroll
    for (int c = 0; c < 4; ++c) {
        float sum = s_i + t[c];
        float lr  = fmaxf(sum, 0.2f * sum);
        float pp  = __builtin_amdgcn_exp2f(fmaf(lr, L2E, d_i));
        p[c] = (av[c] != 0) ? pp : 0.0f;
    }
}

__global__ __launch_bounds__(512, 4) void k4_attn(const int* __restrict__ Adj,
                                                  const short* __restrict__ WhT,
                                                  const float* __restrict__ s_dst,
                                                  const float* __restrict__ s_src,
                                                  const float* __restrict__ pmax,
                                                  float* __restrict__ nump,
                                                  float* __restrict__ denp) {
    __shared__ union {
        short B[2][256 * 64];    // [buf][n][8 slots x 8 shorts], slot=c^(n&7); 2x32KB
        float red[8 * 16 * 64];  // epilogue: [w][reg][lane]; 32KB
    } sm;
    __shared__ float denred[4 * 32];

    const int tid = threadIdx.x;
    const int w = tid >> 6, lane = tid & 63;
    const int jq = w & 3, nh = w >> 2;
    const int l31 = lane & 31, lh = lane >> 5;
    const int ib = (int)blockIdx.x >> 1, jh = (int)blockIdx.x & 1;
    const int i0 = ib * 32;
    const int row = i0 + l31;
    const int jbase = jh * 4096;

    float M = pmax[0];
    #pragma unroll
    for (int b = 1; b < 32; ++b) M = fmaxf(M, pmax[b]);
    const float s_i = s_src[row];
    const float e0 = s_i + M;
    const float d_i = -fmaxf(e0, 0.2f * e0) * L2E;   // c_i >= row max (leaky monotone)

    // ---- staging offsets: wave stages n-rows w*32..w*32+31 (4 async16) ----
    int voff[4];
    #pragma unroll
    for (int v = 0; v < 4; ++v) {
        const int rown = w * 32 + v * 8 + (lane >> 3);
        const int c = (lane & 7) ^ (rown & 7);
        voff[v] = rown * N_NODES + c * 8;            // short offset
    }
    const short* gBbase = WhT + jbase;

    // ---- frag-read offsets: global chunk g = jq*2+lh, slot = g^(n&7) ----
    const int g = jq * 2 + lh;
    int boff[4];
    #pragma unroll
    for (int nt = 0; nt < 4; ++nt) {
        const int n = nh * 128 + nt * 32 + l31;
        boff[nt] = n * 64 + ((g ^ (l31 & 7)) * 8);
    }

    const int j0 = jq * 16 + lh * 8;
    const int* aPtr = Adj + (size_t)row * N_NODES + jbase + j0;
    const float* tPtr = s_dst + jbase + j0;

    floatx16 acc[4] = {};
    float den = 0.f;

    // ---- prologue: stage macro 0 -> buf0; prefetch A(0) ----
    #pragma unroll
    for (int v = 0; v < 4; ++v)
        async16(gBbase + voff[v], &sm.B[0][(w * 32 + v * 8) * 64]);
    int4 a0 = *(const int4*)(aPtr);
    int4 a1 = *(const int4*)(aPtr + 4);
    __syncthreads();

    for (int s = 0; s < 64; ++s) {
        const short* Bc = sm.B[s & 1];
        short* Bn = sm.B[(s & 1) ^ 1];

        // stage macro s+1 (async; lands during this macro's compute)
        if (s < 63) {
            const int jo = (s + 1) * 64;
            #pragma unroll
            for (int v = 0; v < 4; ++v)
                async16(gBbase + jo + voff[v], Bn + (w * 32 + v * 8) * 64);
        }
        // prefetch next macro's A into registers (HBM latency hidden)
        const int an = (s < 63) ? (s + 1) * 64 : s * 64;
        int4 na0 = *(const int4*)(aPtr + an);
        int4 na1 = *(const int4*)(aPtr + an + 4);
        // t for this macro (L2-hot broadcast)
        const float* tp = tPtr + s * 64;
        floatx4 t0 = *(const floatx4*)(tp);
        floatx4 t1 = *(const floatx4*)(tp + 4);

        float p[8];
        pgroup(a0, t0, s_i, d_i, p);
        pgroup(a1, t1, s_i, d_i, p + 4);

        short8 af;
        float ds = 0.f;
        #pragma unroll
        for (int c = 0; c < 8; ++c) { af[c] = f2bf_rn(p[c]); ds += p[c]; }
        den += ds;

        #pragma unroll
        for (int nt = 0; nt < 4; ++nt) {
            short8 b = *(const short8*)(Bc + boff[nt]);
            acc[nt] = __builtin_amdgcn_mfma_f32_32x32x16_bf16(af, b, acc[nt], 0, 0, 0);
        }
        a0 = na0; a1 = na1;

        __syncthreads();   // Bc reads done; staging into Bn landed
    }

    // ---- denominator partial (nh==0 waves; jq x lh slices tile j) ----
    den += __shfl_xor(den, 32);
    if (w < 4 && lane < 32) denred[w * 32 + lane] = den;

    // ---- numerator: reduce 4 jq partials per nt via LDS, store to nump[jh]
    float* numq = nump + (size_t)jh * N_NODES * NF;
    #pragma unroll
    for (int nt = 0; nt < 4; ++nt) {
        #pragma unroll
        for (int rg = 0; rg < 16; ++rg)
            sm.red[(w * 16 + rg) * 64 + lane] = acc[nt][rg];
        __syncthreads();
        if (nt == 0 && tid < 32) {
            float d = denred[tid] + denred[32 + tid] + denred[64 + tid] + denred[96 + tid];
            denp[jh * N_NODES + i0 + tid] = d;
        }
        const int nh2 = w & 1;
        const int rb = (w >> 1) * 4;
        #pragma unroll
        for (int k = 0; k < 4; ++k) {
            const int rg = rb + k;
            float v = sm.red[((nh2 * 4 + 0) * 16 + rg) * 64 + lane]
                    + sm.red[((nh2 * 4 + 1) * 16 + rg) * 64 + lane]
                    + sm.red[((nh2 * 4 + 2) * 16 + rg) * 64 + lane]
                    + sm.red[((nh2 * 4 + 3) * 16 + rg) * 64 + lane];
            const int rrow = (rg & 3) + 8 * (rg >> 2) + 4 * lh;
            const int nn = nh2 * 128 + nt * 32 + l31;
            numq[(size_t)(i0 + rrow) * NF + nn] = v;
        }
        __syncthreads();
    }
}

// ---------------------------------------------------------------------------
// K5: out = GELU( (num0+num1) / (den0+den1) )
// ---------------------------------------------------------------------------
__global__ __launch_bounds__(256) void k5_out(const float* __restrict__ nump,
                                              const float* __restrict__ denp,
                                              float* __restrict__ out) {
    const int idx = blockIdx.x * 256 + threadIdx.x;
    const int i = idx >> 8;
    float num = nump[idx] + nump[N_NODES * NF + idx];
    float den = denp[i] + denp[N_NODES + i];
    float x = num / fmaxf(den, 1e-30f);
    out[idx] = 0.5f * x * (1.0f + erff(x * 0.70710678118f));
}

// ---------------------------------------------------------------------------
extern "C" void kernel_launch(void* const* d_in, const int* in_sizes, int n_in,
                              void* d_out, int out_size, void* d_ws, size_t ws_size,
                              hipStream_t stream) {
    const float* X = (const float*)d_in[0];   // fp32 8192x256
    const int*   A = (const int*)d_in[1];     // int32 8192x8192
    const float* W = (const float*)d_in[2];   // fp32 256x256
    const float* r = (const float*)d_in[3];   // fp32 512
    float* out = (float*)d_out;

    char* wsp = (char*)d_ws;
    short* WhT    = (short*)wsp;                    wsp += (size_t)NF * N_NODES * 2;
    short* Whi    = (short*)wsp;                    wsp += NF * NF * 2;
    short* Wlo    = (short*)wsp;                    wsp += NF * NF * 2;
    float* sp_src = (float*)wsp;                    wsp += 4 * N_NODES * 4;
    float* sp_dst = (float*)wsp;                    wsp += 4 * N_NODES * 4;
    float* s_src  = (float*)wsp;                    wsp += N_NODES * 4;
    float* s_dst  = (float*)wsp;                    wsp += N_NODES * 4;
    float* pmax   = (float*)wsp;                    wsp += 32 * 4;
    float* denp   = (float*)wsp;                    wsp += 2 * N_NODES * 4;
    float* nump   = (float*)wsp;  // 2 x 8192 x 256 fp32 = 16 MB

    kx_split<<<64, 256, 0, stream>>>(W, Whi, Wlo);
    k1_gemm<<<256, 512, 0, stream>>>(X, Whi, Wlo, r, WhT, sp_src, sp_dst);
    k2_sv<<<32, 256, 0, stream>>>(sp_src, sp_dst, s_src, s_dst, pmax);
    k4_attn<<<512, 512, 0, stream>>>(A, WhT, s_dst, s_src, pmax, nump, denp);
    k5_out<<<N_NODES * NF / 256, 256, 0, stream>>>(nump, denp, out);
}